// Round 11
// baseline (571.429 us; speedup 1.0000x reference)
//
#include <hip/hip_runtime.h>

// SynthesisLayer: modulated conv2d 3x3 + demod + noise + bias + lrelu*sqrt(2)
// B=16, CIN=COUT=512, RES=64, WDIM=512

#define NCI  512
#define NCO  512

typedef __attribute__((ext_vector_type(8))) short short8;
typedef __attribute__((ext_vector_type(4))) float f32x4;

#define GLDS16(g, l) __builtin_amdgcn_global_load_lds( \
    (const __attribute__((address_space(1))) void*)(g), \
    (__attribute__((address_space(3))) void*)(l), 16, 0, 0)

static __device__ __forceinline__ unsigned short f2bf(float f) {
  unsigned int u = __float_as_uint(f);
  u += 0x7fffu + ((u >> 16) & 1u);   // RNE
  return (unsigned short)(u >> 16);
}

// ---------------- PK1: styles[b][ci] = m1*m2 + m3 ----------------
__global__ __launch_bounds__(256) void k_styles(
    const float* __restrict__ w, const float* __restrict__ aw,
    const float* __restrict__ ab, float* __restrict__ styles) {
  const int ci0 = blockIdx.x * 32, b = blockIdx.y;
  __shared__ float ws[512];
  __shared__ float pm[3][32];
  const int t = threadIdx.x;
  ws[t] = w[b * 512 + t];
  ws[t + 256] = w[b * 512 + 256 + t];
  __syncthreads();
  const int r = t >> 3, k = t & 7;
#pragma unroll
  for (int pass = 0; pass < 3; ++pass) {
    const float* row = aw + (size_t)(ci0 + r + pass * 512) * 512;
    float a = 0.f;
#pragma unroll 4
    for (int i = 0; i < 16; ++i) {
      float4 v = *(const float4*)(row + i * 32 + k * 4);
      float4 u = *(const float4*)(&ws[i * 32 + k * 4]);
      a += v.x * u.x + v.y * u.y + v.z * u.z + v.w * u.w;
    }
    a += __shfl_xor(a, 1); a += __shfl_xor(a, 2); a += __shfl_xor(a, 4);
    if (k == 0) pm[pass][r] = a;
  }
  __syncthreads();
  if (t < 32) {
    const float g = 0.04419417382415922f;  // 1/sqrt(512)
    int j = ci0 + t;
    float m1 = pm[0][t] * g + ab[j];
    float m2 = pm[1][t] * g + ab[j + 512];
    float m3 = pm[2][t] * g + ab[j + 1024];
    styles[b * 512 + j] = m1 * m2 + m3;
  }
}

// ---------------- PK2: weight -> bf16 fragment-linear wb2 (LDS-tiled), wsq ----------------
// wb2 layout per (ci_blk,co_blk) pair: 18432 shorts = [kk(9)][m(4)][lane(64)][e(8)]
//   lane = ((ci>>3)&3)*16 + (co&15), m=(co>>4)&3, e=ci&7
__global__ __launch_bounds__(256) void k_wt(
    const float* __restrict__ wgt, short* __restrict__ wb2, float* __restrict__ wsq) {
  const int co_blk = blockIdx.x & 7, ci_blk = blockIdx.x >> 3;
  __shared__ short wtile[18432];
  const int t = threadIdx.x;
#pragma unroll
  for (int i = 0; i < 8; ++i) {
    int idx = i * 256 + t;           // 0..2047 = co_l*32 + ci_l
    int co_l = idx >> 5, ci_l = idx & 31;
    int co = co_blk * 64 + co_l, ci = ci_blk * 32 + ci_l;
    const float* p = wgt + ((size_t)co * 512 + ci) * 9;
    int base = (co_l >> 4) * 512 + (((ci_l >> 3) & 3) * 16 + (co_l & 15)) * 8 + (ci_l & 7);
    float s = 0.f;
#pragma unroll
    for (int kk = 0; kk < 9; ++kk) {
      float v = p[kk];
      s += v * v;
      wtile[kk * 2048 + base] = (short)f2bf(v);
    }
    wsq[(size_t)co * 512 + ci] = s;
  }
  __syncthreads();
  short8* dst = (short8*)(wb2 + (size_t)(ci_blk * 8 + co_blk) * 18432);
  const short8* src = (const short8*)wtile;
#pragma unroll
  for (int j = 0; j < 9; ++j) dst[j * 256 + t] = src[j * 256 + t];
}

// ---------------- PK3: dcoef[b][co] = rsqrt(sum_ci wsq*s^2 + 1e-8) ----------------
__global__ __launch_bounds__(256) void k_dcoef(
    const float* __restrict__ wsq, const float* __restrict__ styles,
    float* __restrict__ dcoef) {
  const int co0 = blockIdx.x * 32, b = blockIdx.y;
  __shared__ float ss[512];
  const int t = threadIdx.x;
  float s0 = styles[b * 512 + t], s1 = styles[b * 512 + 256 + t];
  ss[t] = s0 * s0;
  ss[t + 256] = s1 * s1;
  __syncthreads();
  const int r = t >> 3, k = t & 7;
  const float* row = wsq + (size_t)(co0 + r) * 512;
  float a = 0.f;
#pragma unroll 4
  for (int i = 0; i < 16; ++i) {
    float4 v = *(const float4*)(row + i * 32 + k * 4);
    float4 u = *(const float4*)(&ss[i * 32 + k * 4]);
    a += v.x * u.x + v.y * u.y + v.z * u.z + v.w * u.w;
  }
  a += __shfl_xor(a, 1); a += __shfl_xor(a, 2); a += __shfl_xor(a, 4);
  if (k == 0) dcoef[b * 512 + co0 + r] = 1.0f / sqrtf(a + 1e-8f);
}

// ---------------- PK4: xt[b][px][ci] = bf16(x[b][ci][px] * styles[b][ci]) ----------------
// grid (64, 16) = 1024 blocks; internal loop over 16 ci-chunks (was 16384 tiny blocks).
__global__ __launch_bounds__(256) void k_xt(
    const float* __restrict__ x, const float* __restrict__ styles,
    short* __restrict__ xt) {
  const int px0 = blockIdx.x * 64, b = blockIdx.y;
  __shared__ float tile[32][68];
  const int t = threadIdx.x;
  const int cil = t >> 4, pxq = t & 15;
  const int pxl = t >> 2, cig = t & 3;
  for (int cc = 0; cc < 16; ++cc) {
    const int ci0 = cc * 32;
#pragma unroll
    for (int half = 0; half < 2; ++half) {
      const int c = cil + half * 16;
      float4 v = *(const float4*)(x + ((size_t)(b * 512 + ci0 + c)) * 4096 + px0 + pxq * 4);
      float sc = styles[b * 512 + ci0 + c];
      v.x *= sc; v.y *= sc; v.z *= sc; v.w *= sc;
      *(float4*)(&tile[c][4 * (pxq ^ (c & 15))]) = v;
    }
    __syncthreads();
    {
      short8 o;
#pragma unroll
      for (int e = 0; e < 8; ++e) {
        int R = cig * 8 + e;
        o[e] = (short)f2bf(tile[R][4 * ((pxl >> 2) ^ (R & 15)) + (pxl & 3)]);
      }
      *(short8*)(xt + ((size_t)(b * 4096 + px0 + pxl)) * 512 + ci0 + cig * 8) = o;
    }
    __syncthreads();   // next chunk overwrites tile
  }
}

// ---------------- conv: implicit GEMM, 64co x (8 rows x 64 w) per block ----------------
// v3: FULL double-buffered 2-phase pipeline (T3-lite). LDS 158.2 KB -> 1 block/CU,
// 1 wave/SIMD. MFMA pipe wall is per-SIMD throughput; single wave issues ds_reads in
// MFMA issue gaps. One __syncthreads per K-step (implicit vmcnt0+lgkmcnt0 makes the
// single barrier race-free: reads of buf drained before anyone re-stages it).
__global__ __launch_bounds__(256, 1) void k_conv(
    const short* __restrict__ xt, const short* __restrict__ wb2,
    const float* __restrict__ dcoef, const float* __restrict__ bias,
    const float* __restrict__ noise, const float* __restrict__ nstr,
    float* __restrict__ out) {
  // XCD mapping v2: 8 co-blocks of one (b,h0) pair consecutive on one XCD.
  const int bid = blockIdx.x;              // 1024 blocks
  const int logical = (bid & 7) * 128 + (bid >> 3);
  const int coi  = logical & 7;
  const int pair = logical >> 3;           // 0..127 = b*8 + h0blk
  const int b    = pair >> 3;
  const int h0   = (pair & 7) * 8;
  const int co0  = coi * 64;

  __shared__ short xs[2][10][4][66][8];    // 84480 B
  __shared__ short wls[2][9][4][64][8];    // 73728 B  (total 158208 B)
  const int t = threadIdx.x;
  const int lane = t & 63, wave = t >> 6;
  const int lrow = lane & 15, lq = lane >> 4;

  const short8 z8 = {0, 0, 0, 0, 0, 0, 0, 0};
  // halo columns 0/65 of every (buf, r, plane): 2*10*4*2 = 160 chunks of 16B
  for (int i2 = t; i2 < 160; i2 += 256) {
    int nb = i2 / 80, j = i2 % 80, r = j / 8, pc = j & 7;
    *(short8*)(&xs[nb][r][pc >> 1][(pc & 1) ? 65 : 0][0]) = z8;
  }
  // out-of-bounds row slabs stay zero (never staged); 264 chunks per buf -> strided.
  if (h0 == 0) {
    for (int i2 = t; i2 < 528; i2 += 256)
      ((short8*)&xs[i2 / 264][0][0][0][0])[i2 % 264] = z8;
  }
  if (h0 == 56) {
    for (int i2 = t; i2 < 528; i2 += 256)
      ((short8*)&xs[i2 / 264][9][0][0][0])[i2 % 264] = z8;
  }

  f32x4 acc[4][8];
#pragma unroll
  for (int m = 0; m < 4; ++m)
#pragma unroll
    for (int n = 0; n < 8; ++n)
#pragma unroll
      for (int e = 0; e < 4; ++e) acc[m][n][e] = 0.f;

  const size_t xb = (size_t)b * 4096 * 512;

  // ---- stage helper (macro-free lambda) ----
  auto stage = [&](int nb, int cb) {
    const int ci0 = cb * 32;
#pragma unroll
    for (int i2 = 0; i2 < 10; ++i2) {          // X: 10 rows x 4 planes
      int r = i2, p = wave;
      int row = h0 - 1 + r;
      if ((unsigned)row < 64u) {
        const short* g = xt + xb + ((size_t)(row * 64 + lane)) * 512 + ci0 + p * 8;
        GLDS16(g, &xs[nb][r][p][1][0]);
      }
    }
    const short* wbase = wb2 + (size_t)(cb * 8 + coi) * 18432;
#pragma unroll
    for (int i2 = 0; i2 < 9; ++i2) {           // W: 36 wave-stages
      int c = i2 * 4 + wave;
      GLDS16(wbase + c * 512 + lane * 8, ((short*)&wls[nb][0][0][0][0]) + c * 512);
    }
  };

  // prologue: stage tile 0 into buf 0
  stage(0, 0);
  __syncthreads();

  int cur = 0;
  for (int cb = 0; cb < 16; ++cb) {
    if (cb < 15) stage(cur ^ 1, cb + 1);       // issue next-tile loads FIRST

    // ---- compute from buf[cur] ----
#pragma unroll
    for (int kw = 0; kw < 3; ++kw) {
      short8 bx[4][4];
#pragma unroll
      for (int r = 0; r < 4; ++r)
#pragma unroll
        for (int c = 0; c < 4; ++c)
          bx[r][c] = *(const short8*)(&xs[cur][2 * wave + r][lq][c * 16 + lrow + kw][0]);
#pragma unroll
      for (int kh = 0; kh < 3; ++kh) {
        const int kk = kh * 3 + kw;
        short8 af[4];
#pragma unroll
        for (int m = 0; m < 4; ++m)
          af[m] = *(const short8*)(&wls[cur][kk][m][lane][0]);
#pragma unroll
        for (int m = 0; m < 4; ++m)
#pragma unroll
          for (int n = 0; n < 8; ++n)
            acc[m][n] = __builtin_amdgcn_mfma_f32_16x16x32_bf16(
                af[m], bx[kh + (n >> 2)][n & 3], acc[m][n], 0, 0, 0);
      }
    }
    __syncthreads();   // drains my ds_reads (lgkmcnt) + next-tile stages (vmcnt)
    cur ^= 1;
  }

  // ---- epilogue: demod, noise, bias, lrelu*sqrt(2) ----
  const float ns = nstr[0];
  float dc[4][4], bv[4][4];
#pragma unroll
  for (int m = 0; m < 4; ++m)
#pragma unroll
    for (int r = 0; r < 4; ++r) {
      int co = co0 + m * 16 + lq * 4 + r;
      dc[m][r] = dcoef[b * NCO + co];
      bv[m][r] = bias[co];
    }
#pragma unroll
  for (int n = 0; n < 8; ++n) {
    int h = h0 + 2 * wave + (n >> 2);
    int wcol = (n & 3) * 16 + lrow;
    float nz = noise[h * 64 + wcol] * ns;
#pragma unroll
    for (int m = 0; m < 4; ++m) {
#pragma unroll
      for (int r = 0; r < 4; ++r) {
        int co = co0 + m * 16 + lq * 4 + r;
        float v = acc[m][n][r] * dc[m][r] + nz + bv[m][r];
        v = (v > 0.f ? v : 0.2f * v) * 1.4142135623730951f;
        out[(((size_t)b * NCO + co) * 64 + h) * 64 + wcol] = v;
      }
    }
  }
}

extern "C" void kernel_launch(void* const* d_in, const int* in_sizes, int n_in,
                              void* d_out, int out_size, void* d_ws, size_t ws_size,
                              hipStream_t stream) {
  const float* x    = (const float*)d_in[0];
  const float* w    = (const float*)d_in[1];
  const float* aw   = (const float*)d_in[2];
  const float* ab   = (const float*)d_in[3];
  const float* wgt  = (const float*)d_in[4];
  const float* bias = (const float*)d_in[5];
  const float* nc   = (const float*)d_in[6];
  const float* ns   = (const float*)d_in[7];
  float* out = (float*)d_out;

  char* ws = (char*)d_ws;
  float* styles = (float*)(ws);                 // 32 KB
  float* dcoef  = (float*)(ws + 32768);         // 32 KB
  float* wsq    = (float*)(ws + 65536);         // 1 MB
  short* wb2    = (short*)(ws + 1114112);       // 4.5 MB
  short* xt     = (short*)(ws + 5832704);       // 64 MB

  k_styles<<<dim3(16, 16), dim3(256), 0, stream>>>(w, aw, ab, styles);
  k_wt<<<dim3(128), dim3(256), 0, stream>>>(wgt, wb2, wsq);
  k_dcoef<<<dim3(16, 16), dim3(256), 0, stream>>>(wsq, styles, dcoef);
  k_xt<<<dim3(64, 16), dim3(256), 0, stream>>>(x, styles, xt);
  k_conv<<<dim3(1024), dim3(256), 0, stream>>>(xt, wb2, dcoef, bias, nc, ns, out);
}